// Round 7
// baseline (128.665 us; speedup 1.0000x reference)
//
#include <hip/hip_runtime.h>

// QCNN: 8 qubits, 256 amplitudes. R7: TWO batch elements per wave.
// Lane l holds amplitudes i = (l<<2)|j, j=0..3 for BOTH elements (independent
// register sets). Qubit q <-> bit (7-q) of i: q=0..5 lane bits 5..0,
// q=6 j bit1, q=7 j bit0.
// R6 was dependency-latency-bound (VALUBusy 75%, DS ~55%, 25% idle): one
// serial swizzle->fma chain per wave. Two elements give two independent
// chains per wave; lane geometry, control masks and uniform constants are
// shared. Gate math stays float2-packed (v_pk_fma_f32).

#define NQ 8

typedef float v2 __attribute__((ext_vector_type(2)));

__device__ __forceinline__ v2 sp(float x) { return (v2){x, x}; }
__device__ __forceinline__ v2 fma2(v2 a, v2 b, v2 c) { return __builtin_elementwise_fma(a, b, c); }
__device__ __forceinline__ v2 swp(v2 v) { return __builtin_shufflevector(v, v, 1, 0); }

template<int M>
__device__ __forceinline__ float sx(float v) {
    if constexpr (M == 32) return __shfl_xor(v, 32, 64);                // cross-half bpermute
    else return __int_as_float(__builtin_amdgcn_ds_swizzle(
                 __float_as_int(v), (M << 10) | 0x1F));                 // BitMode xor
}
template<int M>
__device__ __forceinline__ v2 sx2(v2 v) {
    v2 r; r.x = sx<M>(v.x); r.y = sx<M>(v.y); return r;
}
__device__ __forceinline__ float bperm(int byte_addr, float v) {
    return __int_as_float(__builtin_amdgcn_ds_bpermute(byte_addr, __float_as_int(v)));
}

#define FOR_E _Pragma("unroll") for (int e = 0; e < 2; ++e)

// ---- phase-1 gates (real state A[e]={a0,a1}, B[e]={a2,a3}) ----
#define RY_L(q, M) do { FOR_E { \
    v2 oA = sx2<M>(A[e]), oB = sx2<M>(B[e]); \
    A[e] = fma2(sp(c[e][q]), A[e], sp(ts[e][q]) * oA); \
    B[e] = fma2(sp(c[e][q]), B[e], sp(ts[e][q]) * oB); } \
} while(0)

#define CNOT_FUSED() do { FOR_E { \
    v2 TA = pb ? B[e] : A[e]; \
    v2 TS = pb ? A[e] : B[e]; \
    A[e] = (v2){ bperm(ba0, TA.x), bperm(ba1, TA.y) }; \
    B[e] = (v2){ bperm(ba0, TS.y), bperm(ba1, TS.x) }; } \
} while(0)

// ---- phase-2 gates (complex, Ra/Rb/Ia/Ib per element) ----
#define CRX_LL(CSH, M, cc, sn) do { \
    const bool ct_ = (l >> (CSH)) & 1; \
    v2 oRa[2], oIa[2], oRb[2], oIb[2]; \
    FOR_E { oRa[e]=sx2<M>(Ra[e]); oIa[e]=sx2<M>(Ia[e]); \
            oRb[e]=sx2<M>(Rb[e]); oIb[e]=sx2<M>(Ib[e]); } \
    if (ct_) { FOR_E { \
        Ra[e] = fma2(sp(cc), Ra[e], sp(sn)    * oIa[e]); \
        Ia[e] = fma2(sp(cc), Ia[e], sp(-(sn)) * oRa[e]); \
        Rb[e] = fma2(sp(cc), Rb[e], sp(sn)    * oIb[e]); \
        Ib[e] = fma2(sp(cc), Ib[e], sp(-(sn)) * oRb[e]); } } \
} while(0)

#define RYC0(M, T) do { FOR_E { \
    v2 oRa = sx2<M>(Ra[e]), oIa = sx2<M>(Ia[e]), oRb = sx2<M>(Rb[e]), oIb = sx2<M>(Ib[e]); \
    Ra[e] = fma2(sp(uct0), Ra[e], sp(T) * oRa); Ia[e] = fma2(sp(uct0), Ia[e], sp(T) * oIa); \
    Rb[e] = fma2(sp(uct0), Rb[e], sp(T) * oRb); Ib[e] = fma2(sp(uct0), Ib[e], sp(T) * oIb); } \
} while(0)

// ---- prep kernel: uniform gate constants + layer-0 diag table -> ws ----
// ws[0..3]   crc0, crs0, crc1, crs1
// ws[4..5]   uct0, ust0
// ws[8..13]  uct1, ust1, cl1, sl1, cp1, sp1
// ws[14..19] u01r1, u01i1, u10r1, u10i1, u11r1, u11i1
// ws[20+k*8] k=0..3: cos/sin(k,k+1 lm0), cos/sin(k,k+1 ph0)
__global__ void qcnn_prep(const float* __restrict__ crx,
                          const float* __restrict__ u3p,
                          float* __restrict__ ws) {
    if (threadIdx.x == 0 && blockIdx.x == 0) {
        float sc0, cc0, sc1, cc1;
        __sincosf(0.5f * crx[0], &sc0, &cc0);
        __sincosf(0.5f * crx[1], &sc1, &cc1);
        ws[0] = cc0; ws[1] = sc0; ws[2] = cc1; ws[3] = sc1;
        float lm0, ph0;
        {
            float th = u3p[0]; ph0 = u3p[1]; lm0 = u3p[2];
            float st_, ct_;
            __sincosf(0.5f * th, &st_, &ct_);
            ws[4] = ct_; ws[5] = st_;
        }
        {
            float th = u3p[3], ph = u3p[4], lm = u3p[5];
            float st_, ct_, sl, cl, sp_, cp, spl, cpl;
            __sincosf(0.5f * th, &st_, &ct_);
            __sincosf(lm, &sl, &cl);
            __sincosf(ph, &sp_, &cp);
            __sincosf(ph + lm, &spl, &cpl);
            ws[8] = ct_;  ws[9] = st_;  ws[10] = cl; ws[11] = sl; ws[12] = cp; ws[13] = sp_;
            ws[14] = -st_ * cl;  ws[15] = -st_ * sl;   // u01
            ws[16] =  st_ * cp;  ws[17] =  st_ * sp_;  // u10
            ws[18] =  ct_ * cpl; ws[19] =  ct_ * spl;  // u11
        }
        for (int k = 0; k < 4; ++k) {
            float kf = (float)k;
            float sA0, cA0, sB0, cB0, sA1, cA1, sB1, cB1;
            __sincosf(kf * lm0,         &sA0, &cA0);
            __sincosf((kf + 1.f) * lm0, &sB0, &cB0);
            __sincosf(kf * ph0,         &sA1, &cA1);
            __sincosf((kf + 1.f) * ph0, &sB1, &cB1);
            float* q = ws + 20 + k * 8;
            q[0] = cA0; q[1] = sA0; q[2] = cB0; q[3] = sB0;
            q[4] = cA1; q[5] = sA1; q[6] = cB1; q[7] = sB1;
        }
    }
}

__global__ __launch_bounds__(256) void qcnn_kernel(
    const float* __restrict__ x,
    const float* __restrict__ ws,
    const float* __restrict__ w1,
    const float* __restrict__ b1,
    const float* __restrict__ w2,
    const float* __restrict__ b2,
    float* __restrict__ out,
    int Btot)
{
    const int gtid = blockIdx.x * blockDim.x + threadIdx.x;
    const int w = gtid >> 6;           // wave index
    const int l = threadIdx.x & 63;
    const int e0 = w * 2;              // first of the two elements
    if (e0 >= Btot) return;

    // hoisted per-lane constants for fused CNOT
    const bool pb = __builtin_popcount(l) & 1;
    const int addr0 = (l & 32) | ((l ^ (l >> 1)) & 31);
    const int ba0 = addr0 << 2;
    const int ba1 = ba0 ^ (48 << 2);

    // per-element RY coefficients + signed sines + initial product state
    float c[2][8], s6[2], s7[2], ts[2][6];
    v2 A[2], B[2];
    FOR_E {
        const float4* xv = (const float4*)(x + (e0 + e) * NQ);
        float4 xa = xv[0], xb = xv[1];
        float ang[NQ] = {xa.x, xa.y, xa.z, xa.w, xb.x, xb.y, xb.z, xb.w};
        float sq[NQ];
#pragma unroll
        for (int q = 0; q < NQ; ++q) __sincosf(0.5f * ang[q], &sq[q], &c[e][q]);
#pragma unroll
        for (int q = 0; q < 6; ++q) ts[e][q] = ((l >> (5 - q)) & 1) ? sq[q] : -sq[q];
        s6[e] = sq[6]; s7[e] = sq[7];
        // cycle-1 RY analytically: amp(i) = prod_q (bit_q(i) ? s_q : c_q)
        float pl = (((l >> 5) & 1) ? sq[0] : c[e][0]);
        pl *= (((l >> 4) & 1) ? sq[1] : c[e][1]);
        pl *= (((l >> 3) & 1) ? sq[2] : c[e][2]);
        pl *= (((l >> 2) & 1) ? sq[3] : c[e][3]);
        pl *= (((l >> 1) & 1) ? sq[4] : c[e][4]);
        pl *= ((l & 1) ? sq[5] : c[e][5]);
        v2 cs7 = {c[e][7], sq[7]};
        A[e] = sp(pl * c[e][6]) * cs7;
        B[e] = sp(pl * sq[6]) * cs7;
    }

    // uniform constants
    const float crc0 = ws[0], crs0 = ws[1], crc1 = ws[2], crs1 = ws[3];
    const float uct0 = ws[4], ust0 = ws[5];
    const float uct1 = ws[8],  ust1 = ws[9],  cl1 = ws[10], sl1 = ws[11], cp1 = ws[12], sp1 = ws[13];
    const float u01r1 = ws[14], u01i1 = ws[15], u10r1 = ws[16], u10i1 = ws[17], u11r1 = ws[18], u11i1 = ws[19];

    // layer-0 fused-U3 diag phases from table (k = b4+b2+b0) — lane geometry, shared
    const int ki = ((l >> 4) & 1) + ((l >> 2) & 1) + (l & 1);
    const float4* dtab = (const float4*)(ws + 20 + ki * 8);
    float4 d0 = dtab[0], d1 = dtab[1];
    const v2 CAB_lm = {d0.x, d0.z}, SAB_lm = {d0.y, d0.w};
    const v2 CAB_ph = {d1.x, d1.z}, SAB_ph = {d1.y, d1.w};
    const float tu1 = ((l >> 4) & 1) ? ust0 : -ust0;
    const float tu3 = ((l >> 2) & 1) ? ust0 : -ust0;
    const float tu5 = (l & 1)        ? ust0 : -ust0;

    // ================= Phase 1 =================
    CNOT_FUSED();
#pragma unroll
    for (int cyc = 0; cyc < 3; ++cyc) {
        RY_L(0, 32); RY_L(1, 16); RY_L(2, 8); RY_L(3, 4); RY_L(4, 2); RY_L(5, 1);
        FOR_E { // RY q=6: elementwise across A,B
            v2 nA = fma2(sp(-s6[e]), B[e], sp(c[e][6]) * A[e]);
            B[e] = fma2(sp(c[e][6]), B[e], sp(s6[e]) * A[e]);
            A[e] = nA;
        }
        FOR_E { // RY q=7: within-vector
            v2 sv = {-s7[e], s7[e]};
            A[e] = fma2(sp(c[e][7]), A[e], sv * swp(A[e]));
            B[e] = fma2(sp(c[e][7]), B[e], sv * swp(B[e]));
        }
        CNOT_FUSED();
    }

    // ================= Phase 2 (complex, packed) ===========================
    v2 Ra[2], Rb[2], Ia[2], Ib[2];
    FOR_E { Ra[e] = A[e]; Rb[e] = B[e]; Ia[e] = sp(0.f); Ib[e] = sp(0.f); }

    // Layer 0, first sublayer: (0,1) real-state fast path, then (2,3),(4,5),(6,7)
    {
        const bool ct_ = (l >> 5) & 1;
        v2 oRa[2], oRb[2];
        FOR_E { oRa[e] = sx2<16>(Ra[e]); oRb[e] = sx2<16>(Rb[e]); }
        if (ct_) { FOR_E {
            Ia[e] = sp(-crs0) * oRa[e]; Ra[e] = sp(crc0) * Ra[e];
            Ib[e] = sp(-crs0) * oRb[e]; Rb[e] = sp(crc0) * Rb[e];
        } }
    }
    CRX_LL(3, 4, crc0, crs0);          // (2,3)
    CRX_LL(1, 1, crc0, crs0);          // (4,5)
    FOR_E { // (6,7): in-lane pair on regs (2,3) = within Rb/Ib
        v2 nRb = fma2(sp(crc0), Rb[e], sp(crs0) * swp(Ib[e]));
        Ib[e] = fma2(sp(crc0), Ib[e], sp(-crs0) * swp(Rb[e]));   // uses old Rb
        Rb[e] = nRb;
    }
    // second sublayer: (1,2),(3,4),(5,6)
    CRX_LL(4, 8, crc0, crs0);
    CRX_LL(2, 2, crc0, crs0);
    if (l & 1) { FOR_E { // (5,6): pairs (0,2),(1,3): a<->b elementwise
        v2 nRa = fma2(sp(crc0), Ra[e], sp(crs0) * Ib[e]);
        v2 nRb = fma2(sp(crc0), Rb[e], sp(crs0) * Ia[e]);
        v2 nIa = fma2(sp(crc0), Ia[e], sp(-crs0) * Rb[e]);
        v2 nIb = fma2(sp(crc0), Ib[e], sp(-crs0) * Ra[e]);
        Ra[e] = nRa; Rb[e] = nRb; Ia[e] = nIa; Ib[e] = nIb;
    } }
    // ---- fused layer-0 U3 on q1,q3,q5,q7: [D2][RY x4][D1] ----
    FOR_E { // D1 (lm0 phases)
        v2 nRa = fma2(CAB_lm, Ra[e], -SAB_lm * Ia[e]);
        Ia[e] = fma2(CAB_lm, Ia[e], SAB_lm * Ra[e]); Ra[e] = nRa;
        v2 nRb = fma2(CAB_lm, Rb[e], -SAB_lm * Ib[e]);
        Ib[e] = fma2(CAB_lm, Ib[e], SAB_lm * Rb[e]); Rb[e] = nRb;
    }
    RYC0(16, tu1);                     // RY(th0) q=1
    RYC0(4,  tu3);                     // RY(th0) q=3
    RYC0(1,  tu5);                     // RY(th0) q=5
    FOR_E { // RY(th0) q=7: within-vector, real coefficients
        v2 usv = {-ust0, ust0};
        Ra[e] = fma2(sp(uct0), Ra[e], usv * swp(Ra[e]));
        Rb[e] = fma2(sp(uct0), Rb[e], usv * swp(Rb[e]));
        Ia[e] = fma2(sp(uct0), Ia[e], usv * swp(Ia[e]));
        Ib[e] = fma2(sp(uct0), Ib[e], usv * swp(Ib[e]));
    }
    FOR_E { // D2 (ph0 phases)
        v2 nRa = fma2(CAB_ph, Ra[e], -SAB_ph * Ia[e]);
        Ia[e] = fma2(CAB_ph, Ia[e], SAB_ph * Ra[e]); Ra[e] = nRa;
        v2 nRb = fma2(CAB_ph, Rb[e], -SAB_ph * Ib[e]);
        Ib[e] = fma2(CAB_ph, Ib[e], SAB_ph * Rb[e]); Rb[e] = nRb;
    }

    // Layer 1: CRX (1,3),(5,7) then (3,5); U3 on 3,7
    CRX_LL(4, 4, crc1, crs1);          // (1,3)
    if (l & 1) { FOR_E { // (5,7): within-vector pairs (0,1),(2,3)
        v2 nRa = fma2(sp(crc1), Ra[e], sp(crs1) * swp(Ia[e]));
        v2 nIa = fma2(sp(crc1), Ia[e], sp(-crs1) * swp(Ra[e]));
        v2 nRb = fma2(sp(crc1), Rb[e], sp(crs1) * swp(Ib[e]));
        v2 nIb = fma2(sp(crc1), Ib[e], sp(-crs1) * swp(Rb[e]));
        Ra[e] = nRa; Ia[e] = nIa; Rb[e] = nRb; Ib[e] = nIb;
    } }
    CRX_LL(2, 1, crc1, crs1);          // (3,5)
    { // U3 layer 1 on q=3 (lane bit2, mask 4): D(lm) RY(th) D(ph)
        const bool b = (l >> 2) & 1;
        if (b) { FOR_E {
            v2 nRa = fma2(sp(cl1), Ra[e], sp(-sl1) * Ia[e]);
            Ia[e] = fma2(sp(cl1), Ia[e], sp(sl1) * Ra[e]); Ra[e] = nRa;
            v2 nRb = fma2(sp(cl1), Rb[e], sp(-sl1) * Ib[e]);
            Ib[e] = fma2(sp(cl1), Ib[e], sp(sl1) * Rb[e]); Rb[e] = nRb;
        } }
        const float t = b ? ust1 : -ust1;
        v2 oRa[2], oIa[2], oRb[2], oIb[2];
        FOR_E { oRa[e]=sx2<4>(Ra[e]); oIa[e]=sx2<4>(Ia[e]);
                oRb[e]=sx2<4>(Rb[e]); oIb[e]=sx2<4>(Ib[e]); }
        FOR_E {
            Ra[e] = fma2(sp(uct1), Ra[e], sp(t) * oRa[e]);
            Ia[e] = fma2(sp(uct1), Ia[e], sp(t) * oIa[e]);
            Rb[e] = fma2(sp(uct1), Rb[e], sp(t) * oRb[e]);
            Ib[e] = fma2(sp(uct1), Ib[e], sp(t) * oIb[e]);
        }
        if (b) { FOR_E {
            v2 nRa = fma2(sp(cp1), Ra[e], sp(-sp1) * Ia[e]);
            Ia[e] = fma2(sp(cp1), Ia[e], sp(sp1) * Ra[e]); Ra[e] = nRa;
            v2 nRb = fma2(sp(cp1), Rb[e], sp(-sp1) * Ib[e]);
            Ib[e] = fma2(sp(cp1), Ib[e], sp(sp1) * Rb[e]); Rb[e] = nRb;
        } }
    }
    { // U3 layer 1 on q=7 (j bit0): within-vector complex 2x2
        v2 E0 = {uct1, u11r1}, E1 = {u01r1, u10r1};
        v2 E2 = {0.f, -u11i1}, E3 = {-u01i1, -u10i1};
        v2 G2 = {0.f,  u11i1}, G3 = { u01i1,  u10i1};
        FOR_E {
            v2 sRa = swp(Ra[e]), sIa = swp(Ia[e]), sRb = swp(Rb[e]), sIb = swp(Ib[e]);
            v2 nRa = fma2(E3, sIa, fma2(E2, Ia[e], fma2(E1, sRa, E0 * Ra[e])));
            v2 nIa = fma2(G3, sRa, fma2(G2, Ra[e], fma2(E1, sIa, E0 * Ia[e])));
            v2 nRb = fma2(E3, sIb, fma2(E2, Ib[e], fma2(E1, sRb, E0 * Rb[e])));
            v2 nIb = fma2(G3, sRb, fma2(G2, Rb[e], fma2(E1, sIb, E0 * Ib[e])));
            Ra[e] = nRa; Ia[e] = nIa; Rb[e] = nRb; Ib[e] = nIb;
        }
    }

    // ================= expvals + MLP =================
    v2 F[2];
    const float sgn = ((l >> 2) & 1) ? -1.0f : 1.0f;
    FOR_E {
        v2 Na = fma2(Ia[e], Ia[e], Ra[e] * Ra[e]);
        v2 Nb = fma2(Ib[e], Ib[e], Rb[e] * Rb[e]);
        v2 T = Na + Nb;
        F[e] = (v2){ sgn * (T.x + T.y), T.x - T.y };   // {Z(q3), Z(q7)}
    }
    FOR_E { F[e] += sx2<1>(F[e]); }
    FOR_E { F[e] += sx2<2>(F[e]); }
    FOR_E { F[e] += sx2<4>(F[e]); }
    FOR_E { F[e] += sx2<8>(F[e]); }
    FOR_E { F[e] += sx2<16>(F[e]); }
    FOR_E { F[e] += sx2<32>(F[e]); }

    // merged MLP tail: rows 0,2 -> element 0; rows 1,3 -> element 1.
    // 10 hidden units on lanes k=0..9 of each 16-lane row; ONE exp chain.
    const int k = l & 15;
    const int row = l >> 4;
    const float Fx = (row & 1) ? F[1].x : F[0].x;
    const float Fy = (row & 1) ? F[1].y : F[0].y;
    float contrib = 0.0f;
    if (k < 10) {
        float z = fmaf(Fx, w1[k], fmaf(Fy, w1[10 + k], b1[k]));
        float ex = __expf(2.0f * z);
        float h = (ex - 1.0f) / (ex + 1.0f);
        contrib = h * w2[k];
    }
    contrib += sx<1>(contrib);
    contrib += sx<2>(contrib);
    contrib += sx<4>(contrib);
    contrib += sx<8>(contrib);
    if (k == 0 && row < 2) {
        float a = contrib + b2[0];
        out[e0 + row] = 1.0f / (1.0f + __expf(-a));
    }
}

extern "C" void kernel_launch(void* const* d_in, const int* in_sizes, int n_in,
                              void* d_out, int out_size, void* d_ws, size_t ws_size,
                              hipStream_t stream) {
    const float* x   = (const float*)d_in[0];
    const float* crx = (const float*)d_in[1];
    const float* u3p = (const float*)d_in[2];
    const float* w1  = (const float*)d_in[3];
    const float* b1  = (const float*)d_in[4];
    const float* w2  = (const float*)d_in[5];
    const float* b2  = (const float*)d_in[6];
    float* out = (float*)d_out;
    float* ws  = (float*)d_ws;

    const int B = in_sizes[0] / NQ;              // 65536
    hipLaunchKernelGGL(qcnn_prep, dim3(1), dim3(64), 0, stream, crx, u3p, ws);
    const int waves = (B + 1) / 2;               // 2 elements per wave
    const int wavesPerBlock = 256 / 64;          // 4
    const int grid = (waves + wavesPerBlock - 1) / wavesPerBlock;
    hipLaunchKernelGGL(qcnn_kernel, dim3(grid), dim3(256), 0, stream,
                       x, ws, w1, b1, w2, b2, out, B);
}

// Round 8
// 123.377 us; speedup vs baseline: 1.0429x; 1.0429x over previous
//
#include <hip/hip_runtime.h>

// QCNN: 8 qubits, 256 amplitudes. TWO batch elements per wave.
// Lane l holds amplitudes i = (l<<2)|j, j=0..3 for BOTH elements.
// Qubit q <-> bit (7-q) of i: q=0..5 lane bits 5..0, q=6 j bit1, q=7 j bit0.
//
// R8: R6/R7 plateaued at ~75us = DS-pipe throughput floor (372 ds-ops/wave x
// 128 waves/CU x ~4cyc ~= 180K cycles; VALUBusy only 65%). Rebalance: xor1,
// xor2, xor8 shuffles -> DPP (VALU pipe, 1 op each); xor4/xor16 stay
// ds_swizzle; xor32 + fused-CNOT stay bpermute. 167 of 372 ds-ops/wave move
// to the VALU's ~35% headroom. Gate math stays float2-packed (v_pk_fma_f32).

#define NQ 8

typedef float v2 __attribute__((ext_vector_type(2)));

__device__ __forceinline__ v2 sp(float x) { return (v2){x, x}; }
__device__ __forceinline__ v2 fma2(v2 a, v2 b, v2 c) { return __builtin_elementwise_fma(a, b, c); }
__device__ __forceinline__ v2 swp(v2 v) { return __builtin_shufflevector(v, v, 1, 0); }

template<int CTRL>
__device__ __forceinline__ float dppf(float v) {
    return __int_as_float(__builtin_amdgcn_mov_dpp(__float_as_int(v), CTRL, 0xF, 0xF, true));
}

template<int M>
__device__ __forceinline__ float sx(float v) {
    if constexpr (M == 1)       return dppf<0xB1>(v);                  // quad_perm [1,0,3,2]
    else if constexpr (M == 2)  return dppf<0x4E>(v);                  // quad_perm [2,3,0,1]
    else if constexpr (M == 8)  return dppf<0x128>(v);                 // row_ror:8 = xor8
    else if constexpr (M == 32) return __shfl_xor(v, 32, 64);          // cross-half bpermute
    else return __int_as_float(__builtin_amdgcn_ds_swizzle(
                 __float_as_int(v), (M << 10) | 0x1F));                // BitMode xor (4,16)
}
template<int M>
__device__ __forceinline__ v2 sx2(v2 v) {
    v2 r; r.x = sx<M>(v.x); r.y = sx<M>(v.y); return r;
}
__device__ __forceinline__ float bperm(int byte_addr, float v) {
    return __int_as_float(__builtin_amdgcn_ds_bpermute(byte_addr, __float_as_int(v)));
}

#define FOR_E _Pragma("unroll") for (int e = 0; e < 2; ++e)

// ---- phase-1 gates (real state A[e]={a0,a1}, B[e]={a2,a3}) ----
#define RY_L(q, M) do { FOR_E { \
    v2 oA = sx2<M>(A[e]), oB = sx2<M>(B[e]); \
    A[e] = fma2(sp(c[e][q]), A[e], sp(ts[e][q]) * oA); \
    B[e] = fma2(sp(c[e][q]), B[e], sp(ts[e][q]) * oB); } \
} while(0)

#define CNOT_FUSED() do { FOR_E { \
    v2 TA = pb ? B[e] : A[e]; \
    v2 TS = pb ? A[e] : B[e]; \
    A[e] = (v2){ bperm(ba0, TA.x), bperm(ba1, TA.y) }; \
    B[e] = (v2){ bperm(ba0, TS.y), bperm(ba1, TS.x) }; } \
} while(0)

// ---- phase-2 gates (complex, Ra/Rb/Ia/Ib per element) ----
#define CRX_LL(CSH, M, cc, sn) do { \
    const bool ct_ = (l >> (CSH)) & 1; \
    v2 oRa[2], oIa[2], oRb[2], oIb[2]; \
    FOR_E { oRa[e]=sx2<M>(Ra[e]); oIa[e]=sx2<M>(Ia[e]); \
            oRb[e]=sx2<M>(Rb[e]); oIb[e]=sx2<M>(Ib[e]); } \
    if (ct_) { FOR_E { \
        Ra[e] = fma2(sp(cc), Ra[e], sp(sn)    * oIa[e]); \
        Ia[e] = fma2(sp(cc), Ia[e], sp(-(sn)) * oRa[e]); \
        Rb[e] = fma2(sp(cc), Rb[e], sp(sn)    * oIb[e]); \
        Ib[e] = fma2(sp(cc), Ib[e], sp(-(sn)) * oRb[e]); } } \
} while(0)

#define RYC0(M, T) do { FOR_E { \
    v2 oRa = sx2<M>(Ra[e]), oIa = sx2<M>(Ia[e]), oRb = sx2<M>(Rb[e]), oIb = sx2<M>(Ib[e]); \
    Ra[e] = fma2(sp(uct0), Ra[e], sp(T) * oRa); Ia[e] = fma2(sp(uct0), Ia[e], sp(T) * oIa); \
    Rb[e] = fma2(sp(uct0), Rb[e], sp(T) * oRb); Ib[e] = fma2(sp(uct0), Ib[e], sp(T) * oIb); } \
} while(0)

// ---- prep kernel: uniform gate constants + layer-0 diag table -> ws ----
// ws[0..3]   crc0, crs0, crc1, crs1
// ws[4..5]   uct0, ust0
// ws[8..13]  uct1, ust1, cl1, sl1, cp1, sp1
// ws[14..19] u01r1, u01i1, u10r1, u10i1, u11r1, u11i1
// ws[20+k*8] k=0..3: cos/sin(k,k+1 lm0), cos/sin(k,k+1 ph0)
__global__ void qcnn_prep(const float* __restrict__ crx,
                          const float* __restrict__ u3p,
                          float* __restrict__ ws) {
    if (threadIdx.x == 0 && blockIdx.x == 0) {
        float sc0, cc0, sc1, cc1;
        __sincosf(0.5f * crx[0], &sc0, &cc0);
        __sincosf(0.5f * crx[1], &sc1, &cc1);
        ws[0] = cc0; ws[1] = sc0; ws[2] = cc1; ws[3] = sc1;
        float lm0, ph0;
        {
            float th = u3p[0]; ph0 = u3p[1]; lm0 = u3p[2];
            float st_, ct_;
            __sincosf(0.5f * th, &st_, &ct_);
            ws[4] = ct_; ws[5] = st_;
        }
        {
            float th = u3p[3], ph = u3p[4], lm = u3p[5];
            float st_, ct_, sl, cl, sp_, cp, spl, cpl;
            __sincosf(0.5f * th, &st_, &ct_);
            __sincosf(lm, &sl, &cl);
            __sincosf(ph, &sp_, &cp);
            __sincosf(ph + lm, &spl, &cpl);
            ws[8] = ct_;  ws[9] = st_;  ws[10] = cl; ws[11] = sl; ws[12] = cp; ws[13] = sp_;
            ws[14] = -st_ * cl;  ws[15] = -st_ * sl;   // u01
            ws[16] =  st_ * cp;  ws[17] =  st_ * sp_;  // u10
            ws[18] =  ct_ * cpl; ws[19] =  ct_ * spl;  // u11
        }
        for (int k = 0; k < 4; ++k) {
            float kf = (float)k;
            float sA0, cA0, sB0, cB0, sA1, cA1, sB1, cB1;
            __sincosf(kf * lm0,         &sA0, &cA0);
            __sincosf((kf + 1.f) * lm0, &sB0, &cB0);
            __sincosf(kf * ph0,         &sA1, &cA1);
            __sincosf((kf + 1.f) * ph0, &sB1, &cB1);
            float* q = ws + 20 + k * 8;
            q[0] = cA0; q[1] = sA0; q[2] = cB0; q[3] = sB0;
            q[4] = cA1; q[5] = sA1; q[6] = cB1; q[7] = sB1;
        }
    }
}

__global__ __launch_bounds__(256) void qcnn_kernel(
    const float* __restrict__ x,
    const float* __restrict__ ws,
    const float* __restrict__ w1,
    const float* __restrict__ b1,
    const float* __restrict__ w2,
    const float* __restrict__ b2,
    float* __restrict__ out,
    int Btot)
{
    const int gtid = blockIdx.x * blockDim.x + threadIdx.x;
    const int w = gtid >> 6;           // wave index
    const int l = threadIdx.x & 63;
    const int e0 = w * 2;              // first of the two elements
    if (e0 >= Btot) return;

    // hoisted per-lane constants for fused CNOT
    const bool pb = __builtin_popcount(l) & 1;
    const int addr0 = (l & 32) | ((l ^ (l >> 1)) & 31);
    const int ba0 = addr0 << 2;
    const int ba1 = ba0 ^ (48 << 2);

    // per-element RY coefficients + signed sines + initial product state
    float c[2][8], s6[2], s7[2], ts[2][6];
    v2 A[2], B[2];
    FOR_E {
        const float4* xv = (const float4*)(x + (e0 + e) * NQ);
        float4 xa = xv[0], xb = xv[1];
        float ang[NQ] = {xa.x, xa.y, xa.z, xa.w, xb.x, xb.y, xb.z, xb.w};
        float sq[NQ];
#pragma unroll
        for (int q = 0; q < NQ; ++q) __sincosf(0.5f * ang[q], &sq[q], &c[e][q]);
#pragma unroll
        for (int q = 0; q < 6; ++q) ts[e][q] = ((l >> (5 - q)) & 1) ? sq[q] : -sq[q];
        s6[e] = sq[6]; s7[e] = sq[7];
        // cycle-1 RY analytically: amp(i) = prod_q (bit_q(i) ? s_q : c_q)
        float pl = (((l >> 5) & 1) ? sq[0] : c[e][0]);
        pl *= (((l >> 4) & 1) ? sq[1] : c[e][1]);
        pl *= (((l >> 3) & 1) ? sq[2] : c[e][2]);
        pl *= (((l >> 2) & 1) ? sq[3] : c[e][3]);
        pl *= (((l >> 1) & 1) ? sq[4] : c[e][4]);
        pl *= ((l & 1) ? sq[5] : c[e][5]);
        v2 cs7 = {c[e][7], sq[7]};
        A[e] = sp(pl * c[e][6]) * cs7;
        B[e] = sp(pl * sq[6]) * cs7;
    }

    // uniform constants
    const float crc0 = ws[0], crs0 = ws[1], crc1 = ws[2], crs1 = ws[3];
    const float uct0 = ws[4], ust0 = ws[5];
    const float uct1 = ws[8],  ust1 = ws[9],  cl1 = ws[10], sl1 = ws[11], cp1 = ws[12], sp1 = ws[13];
    const float u01r1 = ws[14], u01i1 = ws[15], u10r1 = ws[16], u10i1 = ws[17], u11r1 = ws[18], u11i1 = ws[19];

    // layer-0 fused-U3 diag phases from table (k = b4+b2+b0) — lane geometry, shared
    const int ki = ((l >> 4) & 1) + ((l >> 2) & 1) + (l & 1);
    const float4* dtab = (const float4*)(ws + 20 + ki * 8);
    float4 d0 = dtab[0], d1 = dtab[1];
    const v2 CAB_lm = {d0.x, d0.z}, SAB_lm = {d0.y, d0.w};
    const v2 CAB_ph = {d1.x, d1.z}, SAB_ph = {d1.y, d1.w};
    const float tu1 = ((l >> 4) & 1) ? ust0 : -ust0;
    const float tu3 = ((l >> 2) & 1) ? ust0 : -ust0;
    const float tu5 = (l & 1)        ? ust0 : -ust0;

    // ================= Phase 1 =================
    CNOT_FUSED();
#pragma unroll
    for (int cyc = 0; cyc < 3; ++cyc) {
        RY_L(0, 32); RY_L(1, 16); RY_L(2, 8); RY_L(3, 4); RY_L(4, 2); RY_L(5, 1);
        FOR_E { // RY q=6: elementwise across A,B
            v2 nA = fma2(sp(-s6[e]), B[e], sp(c[e][6]) * A[e]);
            B[e] = fma2(sp(c[e][6]), B[e], sp(s6[e]) * A[e]);
            A[e] = nA;
        }
        FOR_E { // RY q=7: within-vector
            v2 sv = {-s7[e], s7[e]};
            A[e] = fma2(sp(c[e][7]), A[e], sv * swp(A[e]));
            B[e] = fma2(sp(c[e][7]), B[e], sv * swp(B[e]));
        }
        CNOT_FUSED();
    }

    // ================= Phase 2 (complex, packed) ===========================
    v2 Ra[2], Rb[2], Ia[2], Ib[2];
    FOR_E { Ra[e] = A[e]; Rb[e] = B[e]; Ia[e] = sp(0.f); Ib[e] = sp(0.f); }

    // Layer 0, first sublayer: (0,1) real-state fast path, then (2,3),(4,5),(6,7)
    {
        const bool ct_ = (l >> 5) & 1;
        v2 oRa[2], oRb[2];
        FOR_E { oRa[e] = sx2<16>(Ra[e]); oRb[e] = sx2<16>(Rb[e]); }
        if (ct_) { FOR_E {
            Ia[e] = sp(-crs0) * oRa[e]; Ra[e] = sp(crc0) * Ra[e];
            Ib[e] = sp(-crs0) * oRb[e]; Rb[e] = sp(crc0) * Rb[e];
        } }
    }
    CRX_LL(3, 4, crc0, crs0);          // (2,3)
    CRX_LL(1, 1, crc0, crs0);          // (4,5)
    FOR_E { // (6,7): in-lane pair on regs (2,3) = within Rb/Ib
        v2 nRb = fma2(sp(crc0), Rb[e], sp(crs0) * swp(Ib[e]));
        Ib[e] = fma2(sp(crc0), Ib[e], sp(-crs0) * swp(Rb[e]));   // uses old Rb
        Rb[e] = nRb;
    }
    // second sublayer: (1,2),(3,4),(5,6)
    CRX_LL(4, 8, crc0, crs0);
    CRX_LL(2, 2, crc0, crs0);
    if (l & 1) { FOR_E { // (5,6): pairs (0,2),(1,3): a<->b elementwise
        v2 nRa = fma2(sp(crc0), Ra[e], sp(crs0) * Ib[e]);
        v2 nRb = fma2(sp(crc0), Rb[e], sp(crs0) * Ia[e]);
        v2 nIa = fma2(sp(crc0), Ia[e], sp(-crs0) * Rb[e]);
        v2 nIb = fma2(sp(crc0), Ib[e], sp(-crs0) * Ra[e]);
        Ra[e] = nRa; Rb[e] = nRb; Ia[e] = nIa; Ib[e] = nIb;
    } }
    // ---- fused layer-0 U3 on q1,q3,q5,q7: [D2][RY x4][D1] ----
    FOR_E { // D1 (lm0 phases)
        v2 nRa = fma2(CAB_lm, Ra[e], -SAB_lm * Ia[e]);
        Ia[e] = fma2(CAB_lm, Ia[e], SAB_lm * Ra[e]); Ra[e] = nRa;
        v2 nRb = fma2(CAB_lm, Rb[e], -SAB_lm * Ib[e]);
        Ib[e] = fma2(CAB_lm, Ib[e], SAB_lm * Rb[e]); Rb[e] = nRb;
    }
    RYC0(16, tu1);                     // RY(th0) q=1
    RYC0(4,  tu3);                     // RY(th0) q=3
    RYC0(1,  tu5);                     // RY(th0) q=5
    FOR_E { // RY(th0) q=7: within-vector, real coefficients
        v2 usv = {-ust0, ust0};
        Ra[e] = fma2(sp(uct0), Ra[e], usv * swp(Ra[e]));
        Rb[e] = fma2(sp(uct0), Rb[e], usv * swp(Rb[e]));
        Ia[e] = fma2(sp(uct0), Ia[e], usv * swp(Ia[e]));
        Ib[e] = fma2(sp(uct0), Ib[e], usv * swp(Ib[e]));
    }
    FOR_E { // D2 (ph0 phases)
        v2 nRa = fma2(CAB_ph, Ra[e], -SAB_ph * Ia[e]);
        Ia[e] = fma2(CAB_ph, Ia[e], SAB_ph * Ra[e]); Ra[e] = nRa;
        v2 nRb = fma2(CAB_ph, Rb[e], -SAB_ph * Ib[e]);
        Ib[e] = fma2(CAB_ph, Ib[e], SAB_ph * Rb[e]); Rb[e] = nRb;
    }

    // Layer 1: CRX (1,3),(5,7) then (3,5); U3 on 3,7
    CRX_LL(4, 4, crc1, crs1);          // (1,3)
    if (l & 1) { FOR_E { // (5,7): within-vector pairs (0,1),(2,3)
        v2 nRa = fma2(sp(crc1), Ra[e], sp(crs1) * swp(Ia[e]));
        v2 nIa = fma2(sp(crc1), Ia[e], sp(-crs1) * swp(Ra[e]));
        v2 nRb = fma2(sp(crc1), Rb[e], sp(crs1) * swp(Ib[e]));
        v2 nIb = fma2(sp(crc1), Ib[e], sp(-crs1) * swp(Rb[e]));
        Ra[e] = nRa; Ia[e] = nIa; Rb[e] = nRb; Ib[e] = nIb;
    } }
    CRX_LL(2, 1, crc1, crs1);          // (3,5)
    { // U3 layer 1 on q=3 (lane bit2, mask 4): D(lm) RY(th) D(ph)
        const bool b = (l >> 2) & 1;
        if (b) { FOR_E {
            v2 nRa = fma2(sp(cl1), Ra[e], sp(-sl1) * Ia[e]);
            Ia[e] = fma2(sp(cl1), Ia[e], sp(sl1) * Ra[e]); Ra[e] = nRa;
            v2 nRb = fma2(sp(cl1), Rb[e], sp(-sl1) * Ib[e]);
            Ib[e] = fma2(sp(cl1), Ib[e], sp(sl1) * Rb[e]); Rb[e] = nRb;
        } }
        const float t = b ? ust1 : -ust1;
        v2 oRa[2], oIa[2], oRb[2], oIb[2];
        FOR_E { oRa[e]=sx2<4>(Ra[e]); oIa[e]=sx2<4>(Ia[e]);
                oRb[e]=sx2<4>(Rb[e]); oIb[e]=sx2<4>(Ib[e]); }
        FOR_E {
            Ra[e] = fma2(sp(uct1), Ra[e], sp(t) * oRa[e]);
            Ia[e] = fma2(sp(uct1), Ia[e], sp(t) * oIa[e]);
            Rb[e] = fma2(sp(uct1), Rb[e], sp(t) * oRb[e]);
            Ib[e] = fma2(sp(uct1), Ib[e], sp(t) * oIb[e]);
        }
        if (b) { FOR_E {
            v2 nRa = fma2(sp(cp1), Ra[e], sp(-sp1) * Ia[e]);
            Ia[e] = fma2(sp(cp1), Ia[e], sp(sp1) * Ra[e]); Ra[e] = nRa;
            v2 nRb = fma2(sp(cp1), Rb[e], sp(-sp1) * Ib[e]);
            Ib[e] = fma2(sp(cp1), Ib[e], sp(sp1) * Rb[e]); Rb[e] = nRb;
        } }
    }
    { // U3 layer 1 on q=7 (j bit0): within-vector complex 2x2
        v2 E0 = {uct1, u11r1}, E1 = {u01r1, u10r1};
        v2 E2 = {0.f, -u11i1}, E3 = {-u01i1, -u10i1};
        v2 G2 = {0.f,  u11i1}, G3 = { u01i1,  u10i1};
        FOR_E {
            v2 sRa = swp(Ra[e]), sIa = swp(Ia[e]), sRb = swp(Rb[e]), sIb = swp(Ib[e]);
            v2 nRa = fma2(E3, sIa, fma2(E2, Ia[e], fma2(E1, sRa, E0 * Ra[e])));
            v2 nIa = fma2(G3, sRa, fma2(G2, Ra[e], fma2(E1, sIa, E0 * Ia[e])));
            v2 nRb = fma2(E3, sIb, fma2(E2, Ib[e], fma2(E1, sRb, E0 * Rb[e])));
            v2 nIb = fma2(G3, sRb, fma2(G2, Rb[e], fma2(E1, sIb, E0 * Ib[e])));
            Ra[e] = nRa; Ia[e] = nIa; Rb[e] = nRb; Ib[e] = nIb;
        }
    }

    // ================= expvals + MLP =================
    v2 F[2];
    const float sgn = ((l >> 2) & 1) ? -1.0f : 1.0f;
    FOR_E {
        v2 Na = fma2(Ia[e], Ia[e], Ra[e] * Ra[e]);
        v2 Nb = fma2(Ib[e], Ib[e], Rb[e] * Rb[e]);
        v2 T = Na + Nb;
        F[e] = (v2){ sgn * (T.x + T.y), T.x - T.y };   // {Z(q3), Z(q7)}
    }
    FOR_E { F[e] += sx2<1>(F[e]); }
    FOR_E { F[e] += sx2<2>(F[e]); }
    FOR_E { F[e] += sx2<4>(F[e]); }
    FOR_E { F[e] += sx2<8>(F[e]); }
    FOR_E { F[e] += sx2<16>(F[e]); }
    FOR_E { F[e] += sx2<32>(F[e]); }

    // merged MLP tail: rows 0,2 -> element 0; rows 1,3 -> element 1.
    // 10 hidden units on lanes k=0..9 of each 16-lane row; ONE exp chain.
    const int k = l & 15;
    const int row = l >> 4;
    const float Fx = (row & 1) ? F[1].x : F[0].x;
    const float Fy = (row & 1) ? F[1].y : F[0].y;
    float contrib = 0.0f;
    if (k < 10) {
        float z = fmaf(Fx, w1[k], fmaf(Fy, w1[10 + k], b1[k]));
        float ex = __expf(2.0f * z);
        float h = (ex - 1.0f) / (ex + 1.0f);
        contrib = h * w2[k];
    }
    contrib += sx<1>(contrib);
    contrib += sx<2>(contrib);
    contrib += sx<4>(contrib);
    contrib += sx<8>(contrib);
    if (k == 0 && row < 2) {
        float a = contrib + b2[0];
        out[e0 + row] = 1.0f / (1.0f + __expf(-a));
    }
}

extern "C" void kernel_launch(void* const* d_in, const int* in_sizes, int n_in,
                              void* d_out, int out_size, void* d_ws, size_t ws_size,
                              hipStream_t stream) {
    const float* x   = (const float*)d_in[0];
    const float* crx = (const float*)d_in[1];
    const float* u3p = (const float*)d_in[2];
    const float* w1  = (const float*)d_in[3];
    const float* b1  = (const float*)d_in[4];
    const float* w2  = (const float*)d_in[5];
    const float* b2  = (const float*)d_in[6];
    float* out = (float*)d_out;
    float* ws  = (float*)d_ws;

    const int B = in_sizes[0] / NQ;              // 65536
    hipLaunchKernelGGL(qcnn_prep, dim3(1), dim3(64), 0, stream, crx, u3p, ws);
    const int waves = (B + 1) / 2;               // 2 elements per wave
    const int wavesPerBlock = 256 / 64;          // 4
    const int grid = (waves + wavesPerBlock - 1) / wavesPerBlock;
    hipLaunchKernelGGL(qcnn_kernel, dim3(grid), dim3(256), 0, stream,
                       x, ws, w1, b1, w2, b2, out, B);
}